// Round 1
// baseline (573.797 us; speedup 1.0000x reference)
//
#include <hip/hip_runtime.h>

#define NUM_P 16320
#define NUM_C 21
#define THETA 0.01f

// ---------------- Kernel A: per-anchor losses + pos mask ----------------
__global__ __launch_bounds__(256) void anchor_kernel(
    const float* __restrict__ loc, const float* __restrict__ conf,
    const float* __restrict__ arm, const float* __restrict__ loct,
    const int* __restrict__ conft, float* __restrict__ accum,
    int* __restrict__ num_pos, float* __restrict__ rankvals, int total)
{
    __shared__ float tile[256 * NUM_C];
    const int tid = threadIdx.x;
    const int base = blockIdx.x * 256;
    const int cbase = base * NUM_C;
    const int climit = total * NUM_C;
    // coalesced stage of the 21-float conf rows for this block's 256 anchors
    for (int i = tid; i < 256 * NUM_C; i += 256) {
        int g = cbase + i;
        tile[i] = (g < climit) ? conf[g] : 0.f;
    }
    __syncthreads();

    const int a = base + tid;
    float ll = 0.f, cep = 0.f;
    if (a < total) {
        const int b = a / NUM_P;
        const int t = conft[a];
        const float* cf = &tile[tid * NUM_C];  // stride 21 -> conflict-free (gcd(21,32)=1)
        float mx = cf[0];
        #pragma unroll
        for (int j = 1; j < NUM_C; ++j) mx = fmaxf(mx, cf[j]);
        float s = 0.f;
        #pragma unroll
        for (int j = 0; j < NUM_C; ++j) s += __expf(cf[j] - mx);
        const float ce = mx + __logf(s) - cf[t];

        const float a0 = arm[2 * a], a1 = arm[2 * a + 1];
        const float am = fmaxf(a0, a1);
        const float e0 = __expf(a0 - am), e1 = __expf(a1 - am);
        const float p1 = e1 / (e0 + e1);
        const bool pos = (t > 0) && (p1 > THETA);

        if (pos) {
            atomicAdd(&num_pos[b], 1);
            cep = ce;
            #pragma unroll
            for (int j = 0; j < 4; ++j) {
                float d = loc[4 * a + j] - loct[4 * a + j];
                float ad = fabsf(d);
                ll += (ad < 1.f) ? 0.5f * ad * ad : ad - 0.5f;
            }
        }
        rankvals[a] = pos ? 0.f : ce;   // loss_for_rank
    }

    // wave64 reduce, one atomic per wave
    #pragma unroll
    for (int off = 32; off > 0; off >>= 1) {
        ll  += __shfl_down(ll, off, 64);
        cep += __shfl_down(cep, off, 64);
    }
    if ((tid & 63) == 0) {
        if (ll  != 0.f) atomicAdd(&accum[0], ll);
        if (cep != 0.f) atomicAdd(&accum[1], cep);
    }
}

// ---------------- Kernel B: per-row radix-select top-k sum ----------------
// values are all >= 0 so unsigned bit order == float order.
__global__ __launch_bounds__(256) void select_kernel(
    const float* __restrict__ rankvals, const int* __restrict__ num_pos,
    float* __restrict__ accum)
{
    const int b = blockIdx.x;
    const float* row = rankvals + (long long)b * NUM_P;
    const int tid = threadIdx.x;

    __shared__ int hist[256];
    __shared__ unsigned s_prefix;
    __shared__ int s_kk;
    __shared__ float wsum[4];

    int k = min(3 * num_pos[b], NUM_P - 1);
    if (k <= 0) return;  // uniform across block

    unsigned prefix = 0;
    unsigned himask = 0;
    int kk = k;

    #pragma unroll
    for (int pass = 0; pass < 4; ++pass) {
        const int shift = 24 - 8 * pass;
        hist[tid] = 0;
        __syncthreads();
        for (int i = tid; i < NUM_P; i += 256) {
            unsigned u = __float_as_uint(row[i]);
            if ((u & himask) == prefix)
                atomicAdd(&hist[(u >> shift) & 255u], 1);
        }
        __syncthreads();
        if (tid == 0) {
            int cum = 0;
            for (int j = 255; j >= 0; --j) {
                int c = hist[j];
                if (cum + c >= kk) {
                    s_kk = kk - cum;
                    s_prefix = prefix | ((unsigned)j << shift);
                    break;
                }
                cum += c;
            }
        }
        __syncthreads();
        prefix = s_prefix;
        kk = s_kk;
        himask |= (0xFFu << shift);
        __syncthreads();
    }

    const unsigned vbits = prefix;       // k-th largest value (bits)
    const float v = __uint_as_float(vbits);

    float partial = 0.f;
    for (int i = tid; i < NUM_P; i += 256) {
        float x = row[i];
        if (__float_as_uint(x) > vbits) partial += x;
    }
    #pragma unroll
    for (int off = 32; off > 0; off >>= 1)
        partial += __shfl_down(partial, off, 64);
    if ((tid & 63) == 0) wsum[tid >> 6] = partial;
    __syncthreads();
    if (tid == 0) {
        float tot = wsum[0] + wsum[1] + wsum[2] + wsum[3];
        // ties at v contribute kk * v (tie-break by index doesn't change the sum)
        atomicAdd(&accum[2], tot + (float)kk * v);
    }
}

// ---------------- Kernel C: finalize ----------------
__global__ void finalize_kernel(const float* __restrict__ accum,
                                const int* __restrict__ num_pos, int Bn,
                                float* __restrict__ out)
{
    if (threadIdx.x == 0 && blockIdx.x == 0) {
        int N = 0;
        for (int b = 0; b < Bn; ++b) N += num_pos[b];
        float fN = (float)N;
        out[0] = accum[0] / fN;
        out[1] = (accum[1] + accum[2]) / fN;
    }
}

extern "C" void kernel_launch(void* const* d_in, const int* in_sizes, int n_in,
                              void* d_out, int out_size, void* d_ws, size_t ws_size,
                              hipStream_t stream) {
    const float* loc  = (const float*)d_in[0];
    const float* conf = (const float*)d_in[1];
    const float* arm  = (const float*)d_in[2];
    const float* loct = (const float*)d_in[3];
    const int*  conft = (const int*)d_in[4];
    float* out = (float*)d_out;

    const int total = in_sizes[4];          // B * P
    const int Bn = total / NUM_P;

    // ws layout: [0,16): float accum[4]; [64, 64+4B): int num_pos[B]; [1024,...): rankvals
    float* accum   = (float*)d_ws;
    int*   num_pos = (int*)((char*)d_ws + 64);
    float* rankvals = (float*)((char*)d_ws + 1024);

    hipMemsetAsync(d_ws, 0, 1024, stream);

    const int grid = (total + 255) / 256;
    hipLaunchKernelGGL(anchor_kernel, dim3(grid), dim3(256), 0, stream,
                       loc, conf, arm, loct, conft, accum, num_pos, rankvals, total);
    hipLaunchKernelGGL(select_kernel, dim3(Bn), dim3(256), 0, stream,
                       rankvals, num_pos, accum);
    hipLaunchKernelGGL(finalize_kernel, dim3(1), dim3(1), 0, stream,
                       accum, num_pos, Bn, out);
}